// Round 9
// baseline (2780.010 us; speedup 1.0000x reference)
//
#include <hip/hip_runtime.h>
#include <hip/hip_bf16.h>

#define TT   1000
#define BB   256
#define HID  256
#define GD   768
#define XD   192
#define NROW (TT*BB)

typedef __attribute__((ext_vector_type(8))) _Float16 half8;
typedef __attribute__((ext_vector_type(4))) float    float4_t;
typedef __attribute__((ext_vector_type(2))) unsigned uint2_t;

#define MFMA16(A,B,C) __builtin_amdgcn_mfma_f32_16x16x32_f16((A),(B),(C),0,0,0)

__device__ __forceinline__ void gll16(const void* g, void* l) {
  __builtin_amdgcn_global_load_lds((const __attribute__((address_space(1))) void*)g,
                                   (__attribute__((address_space(3))) void*)l, 16, 0, 0);
}

__device__ __forceinline__ unsigned short f2h(float f) {
  _Float16 h = (_Float16)f;                       // RTN-even
  union { _Float16 h; unsigned short u; } c; c.h = h; return c.u;
}
__device__ __forceinline__ uint2_t pk4h(float4_t v) {
  union { _Float16 h[4]; uint2_t u; } c;
  c.h[0] = (_Float16)v.x; c.h[1] = (_Float16)v.y;
  c.h[2] = (_Float16)v.z; c.h[3] = (_Float16)v.w;
  return c.u;
}
__device__ __forceinline__ float4_t h4_to_f4(uint2_t v) {
  union { uint2_t u; _Float16 h[4]; } c; c.u = v;
  float4_t f;
  f.x = (float)c.h[0]; f.y = (float)c.h[1];
  f.z = (float)c.h[2]; f.w = (float)c.h[3];
  return f;
}
__device__ __forceinline__ float sigx(float x) {
  return __builtin_amdgcn_rcpf(1.0f + __builtin_amdgcn_exp2f(-1.4426950408889634f * x));
}
__device__ __forceinline__ float tanhx(float x) {
  return 1.0f - 2.0f * __builtin_amdgcn_rcpf(1.0f + __builtin_amdgcn_exp2f(2.8853900817779268f * x));
}
__device__ __forceinline__ float4_t sig4(float4_t v){ float4_t o; o.x=sigx(v.x); o.y=sigx(v.y); o.z=sigx(v.z); o.w=sigx(v.w); return o; }
__device__ __forceinline__ float4_t tanh4(float4_t v){ float4_t o; o.x=tanhx(v.x); o.y=tanhx(v.y); o.z=tanhx(v.z); o.w=tanhx(v.w); return o; }
__device__ __forceinline__ float gelu1(float v){
  // jax.nn.gelu default = tanh approximation
  float c = v + 0.044715f * v * v * v;
  float e = __builtin_amdgcn_exp2f((0.7978845608028654f * 2.8853900817779268f) * c);
  float th = 1.0f - 2.0f * __builtin_amdgcn_rcpf(1.0f + e);
  return 0.5f * v * (1.0f + th);
}

// ---------------- prep: wiT[n][k] fp16, whF pre-fragmented fp16 ----------------
__global__ void k_prep(const float* __restrict__ wi, const float* __restrict__ wh,
                       unsigned short* __restrict__ wiT, unsigned short* __restrict__ whF)
{
  int tid = blockIdx.x * 256 + threadIdx.x;
  if (tid < GD*XD) {
    int n = tid / XD, k = tid - n*XD;
    wiT[tid] = f2h(wi[(size_t)k*GD + n]);
  }
  int t2 = tid - GD*XD;
  if (t2 >= 0 && t2 < 48*8*64*8) {
    int j = t2 & 7, l = (t2 >> 3) & 63, f = t2 >> 9;
    int mf = f >> 3, kf = f & 7;
    int k = kf*32 + ((l >> 4) << 3) + j;   // A-frag: lane row=l&15 (=ocol), k=(l>>4)*8+j
    int n = (mf << 4) + (l & 15);
    whF[t2] = f2h(wh[(size_t)k*GD + n]);
  }
}

// ---------------- embeddings -> x fp16 [NROW][192] ----------------
__global__ void k_embed(const float* __restrict__ st, const float* __restrict__ ac,
                        const float* __restrict__ rw,
                        const float* __restrict__ Ws, const float* __restrict__ bs,
                        const float* __restrict__ Wa, const float* __restrict__ ba,
                        const float* __restrict__ Wr, const float* __restrict__ br,
                        unsigned short* __restrict__ x)
{
  int lane = threadIdx.x & 63;
  int wid = blockIdx.x * (blockDim.x >> 6) + (threadIdx.x >> 6);
  int nw  = gridDim.x * (blockDim.x >> 6);
  float wsr[64], war[8];
  #pragma unroll
  for (int k = 0; k < 64; ++k) wsr[k] = Ws[k*64 + lane];   // lane j holds Ws[:,j]
  #pragma unroll
  for (int k = 0; k < 8; ++k) war[k] = Wa[k*64 + lane];
  float wrr = Wr[lane];
  float bsv = bs[lane], bav = ba[lane], brv = br[lane];
  for (int row = wid; row < NROW; row += nw) {
    const float4_t* sp = (const float4_t*)(st + (size_t)row*64);
    float a0 = bsv;
    #pragma unroll
    for (int q = 0; q < 16; ++q) {
      float4_t v = sp[q];
      a0 = fmaf(v.x, wsr[4*q+0], a0);
      a0 = fmaf(v.y, wsr[4*q+1], a0);
      a0 = fmaf(v.z, wsr[4*q+2], a0);
      a0 = fmaf(v.w, wsr[4*q+3], a0);
    }
    const float4_t* ap = (const float4_t*)(ac + (size_t)row*8);
    float a1 = bav;
    #pragma unroll
    for (int q = 0; q < 2; ++q) {
      float4_t v = ap[q];
      a1 = fmaf(v.x, war[4*q+0], a1);
      a1 = fmaf(v.y, war[4*q+1], a1);
      a1 = fmaf(v.z, war[4*q+2], a1);
      a1 = fmaf(v.w, war[4*q+3], a1);
    }
    float a2 = fmaf(rw[row], wrr, brv);
    unsigned short* xr = x + (size_t)row*XD;
    xr[lane]       = f2h(gelu1(a0));
    xr[64 + lane]  = f2h(gelu1(a1));
    xr[128 + lane] = f2h(gelu1(a2));
  }
}

// ---------------- gx = x @ wi + bg (fp16 out), output-transposed MFMA ----------------
// out[ocol][rowblock]: A = wiT frags (M=768), B = x frags (N=64 rows/WG), K=192.
__global__ __launch_bounds__(512, 2) void k_gx(const unsigned short* __restrict__ x,
                                               const unsigned short* __restrict__ wiT,
                                               const float* __restrict__ bg,
                                               unsigned short* __restrict__ gx)
{
  __shared__ half8 Xs[24*64];   // 24 B-frags (nf*6+kf), lane-linear
  __shared__ half8 As[16*64];   // 16 A-frags per stage phase
  int lane = threadIdx.x & 63;
  int wv   = threadIdx.x >> 6;
  int b    = lane & 15;
  int g8   = (lane >> 4) << 3;
  int row0 = blockIdx.x * 64;
  #pragma unroll
  for (int i = 0; i < 3; ++i) {
    int c = wv*3 + i, nf = c / 6, kf = c - nf*6;
    gll16(x + (size_t)(row0 + nf*16 + b)*XD + kf*32 + g8, &Xs[c*64]);
  }
  int g4 = g8 >> 1;
  float4_t acc[6][4];
  #pragma unroll
  for (int i = 0; i < 6; ++i) {
    float4_t bgv = *(const float4_t*)(bg + (wv + 8*i)*16 + g4);
    #pragma unroll
    for (int nf = 0; nf < 4; ++nf) acc[i][nf] = bgv;   // bias folded into C-init
  }
  half8 xb[4];
  for (int kf = 0; kf < 6; ++kf) {
    #pragma unroll
    for (int p = 0; p < 3; ++p) {
      __syncthreads();                      // prev phase's reads done
      #pragma unroll
      for (int i2 = 0; i2 < 2; ++i2) {
        int q = wv*2 + i2;
        gll16(wiT + (size_t)((p*16 + q)*16 + b)*XD + kf*32 + g8, &As[q*64]);
      }
      __syncthreads();                      // stage complete (drains vmcnt)
      if (p == 0) {
        #pragma unroll
        for (int nf = 0; nf < 4; ++nf) xb[nf] = Xs[(nf*6 + kf)*64 + lane];
      }
      half8 af0 = As[wv*64 + lane];
      half8 af1 = As[(wv+8)*64 + lane];
      #pragma unroll
      for (int nf = 0; nf < 4; ++nf) {
        acc[2*p  ][nf] = MFMA16(af0, xb[nf], acc[2*p  ][nf]);
        acc[2*p+1][nf] = MFMA16(af1, xb[nf], acc[2*p+1][nf]);
      }
    }
  }
  #pragma unroll
  for (int i = 0; i < 6; ++i) {
    #pragma unroll
    for (int nf = 0; nf < 4; ++nf) {
      size_t idx = (size_t)(row0 + nf*16 + b)*GD + (wv + 8*i)*16 + g4;
      *(uint2_t*)(gx + idx) = pk4h(acc[i][nf]);
    }
  }
}

// ---------------- GRU recurrence v4: 16 waves x 24 frags + STATIC 96 KB LDS ----------------
// The two half-fixes, finally combined:
//  * 16 waves, each owning 16 ocols of z+r+a: weights = 24 frags = 96 regs,
//    working ~30 -> ~126 <= 128  (the only FEASIBLE tier; 8-wave needs 250/256
//    and the allocator never produces edge allocations - rounds 2-5, 8).
//  * STATIC 96 KB LDS so the occupancy model sees it (rounds 6-7 failed only
//    because extern-shared was invisible -> assumed 2 WGs/CU -> 64-reg tier).
// Occupancy arithmetic now closes: 1024-thr WG + 96 KB -> 1 WG/CU -> 4 waves/SIMD
// -> pool 512/4 = 128 regs/wave, agreeing with waves_per_eu(4,4) from both sides.
__global__
__attribute__((amdgpu_flat_work_group_size(1024, 1024), amdgpu_waves_per_eu(4, 4)))
void k_gru(const unsigned short* __restrict__ gx,
           const unsigned short* __restrict__ whF,
           float* __restrict__ out)
{
  __shared__ char smem[98304];     // STATIC: 8KB h + 8KB rh + 2x24KB gx slabs + pad
  char* h_lds  = smem;             // [16][256] fp16, XOR-swizzled, 8 KB
  char* rh_lds = smem + 8192;      // [16][256] fp16, XOR-swizzled, 8 KB
  char* gxb    = smem + 16384;     // 2 x [16][768] fp16 slab (src-preswizzled), 48 KB
  const int tid  = threadIdx.x;
  const int lane = tid & 63;
  const int wv   = tid >> 6;       // 0..15
  const int wg   = blockIdx.x;
  const int b    = lane & 15;
  const int g    = lane >> 4;
  const int kr4  = g << 2;
  const int xm   = (b & 7) << 4;

  // wave wv owns ocols [wv*16, wv*16+16) of z, r AND a: 24 frags = 96 VGPRs.
  half8 wz[8], wr[8], wa[8];
  #pragma unroll
  for (int kf = 0; kf < 8; ++kf) {
    wz[kf] = *(const half8*)(whF + ((size_t)(((     wv)*8 + kf)*64 + lane) << 3));
    wr[kf] = *(const half8*)(whF + ((size_t)(((16 + wv)*8 + kf)*64 + lane) << 3));
    wa[kf] = *(const half8*)(whF + ((size_t)(((32 + wv)*8 + kf)*64 + lane) << 3));
  }
  // Pin: forbid remat-as-reload inside the loop (no-op once resident).
  #pragma unroll
  for (int kf = 0; kf < 8; ++kf) {
    asm volatile("" : "+v"(wz[kf]));
    asm volatile("" : "+v"(wr[kf]));
    asm volatile("" : "+v"(wa[kf]));
  }
  for (int i = tid; i < 2048; i += 1024) ((unsigned*)h_lds)[i] = 0u;   // h0 = 0

  // gx staging: 1536 16B-chunks; thread tid takes chunk tid, threads <512 also 1024+tid.
  // linear LDS dest, pre-swizzled global source (swizzle = ^((brow&7)<<4) within row)
  const int doff0 = tid << 4;
  const int brow0 = doff0 / 1536;
  const int cb0   = doff0 - brow0*1536;
  const int soff0 = brow0*1536 + (cb0 ^ ((brow0 & 7) << 4));
  const int doff1 = (1024 + tid) << 4;
  const int brow1 = doff1 / 1536;
  const int cb1   = doff1 - brow1*1536;
  const int soff1 = brow1*1536 + (cb1 ^ ((brow1 & 7) << 4));
  const bool two  = (tid < 512);   // wave-uniform (waves 0-7)

  const char* gxc = (const char*)gx;
  {
    const char* slab0 = gxc + (size_t)wg*24576;
    gll16(slab0 + soff0, gxb + doff0);
    if (two) gll16(slab0 + soff1, gxb + doff1);
  }
  __syncthreads();   // full drain: t=0 slab ready, h zeroed

  float4_t hf = {0.f, 0.f, 0.f, 0.f};   // fp32 h for owned 4 cols (batch b)
  const char* hb_base = h_lds + b*512;
  const char* rb_base = rh_lds + b*512;
  const int off_z = ((wv*16 + kr4) << 1) ^ xm;

  for (int t = 0; t < TT; ++t) {
    // TOP barrier: counted vmcnt(1) -> this wave's glls done, out-store may stay in flight
    asm volatile("s_waitcnt vmcnt(1) lgkmcnt(0)" ::: "memory");
    __builtin_amdgcn_s_barrier();
    asm volatile("" ::: "memory");   // no memory op hoists above the barrier
    if (t + 1 < TT) {   // prefetch next slab; stays in flight across mid barrier
      const char* slab = gxc + (size_t)(t+1)*393216 + (size_t)wg*24576;
      char* dstb = gxb + 24576*((t+1) & 1);
      gll16(slab + soff0, dstb + doff0);
      if (two) gll16(slab + soff1, dstb + doff1);
    }
    const char* cur = gxb + 24576*(t & 1) + b*1536;
    // ---- phase 1: z,r = sigmoid(gx_zr + wh_zr^T @ h^T) ----
    float4_t az = h4_to_f4(*(const uint2_t*)(cur + off_z));
    float4_t ar = h4_to_f4(*(const uint2_t*)(cur + off_z + 512));
    #pragma unroll
    for (int kf = 0; kf < 8; ++kf) {
      half8 hb = *(const half8*)(hb_base + ((kf*64 + (g << 4)) ^ xm));
      az = MFMA16(wz[kf], hb, az);
      ar = MFMA16(wr[kf], hb, ar);
    }
    float4_t z  = sig4(az);
    float4_t rh = sig4(ar) * hf;   // r*h, all in-lane
    *(uint2_t*)(rh_lds + b*512 + off_z) = pk4h(rh);
    // MID barrier: LDS-only wait, prefetch glls stay outstanding
    asm volatile("s_waitcnt lgkmcnt(0)" ::: "memory");
    __builtin_amdgcn_s_barrier();
    asm volatile("" ::: "memory");
    // ---- phase 2: a = tanh(gx_a + wh_a^T @ (r*h)^T) ----
    float4_t aa = h4_to_f4(*(const uint2_t*)(cur + off_z + 1024));
    #pragma unroll
    for (int kf = 0; kf < 8; ++kf) {
      half8 rb = *(const half8*)(rb_base + ((kf*64 + (g << 4)) ^ xm));
      aa = MFMA16(wa[kf], rb, aa);
    }
    float4_t a  = tanh4(aa);
    float4_t hn = hf + z * (a - hf);   // (1-z)h + z*a
    hf = hn;
    *(uint2_t*)(h_lds + b*512 + off_z) = pk4h(hn);
    float* op = out + (((size_t)t*BB + wg*16 + b) << 8) + wv*16 + kr4;
    *(float4_t*)op = hn;
  }
}

extern "C" void kernel_launch(void* const* d_in, const int* in_sizes, int n_in,
                              void* d_out, int out_size, void* d_ws, size_t ws_size,
                              hipStream_t stream) {
  (void)in_sizes; (void)n_in; (void)out_size; (void)ws_size;
  const float* states  = (const float*)d_in[0];
  const float* actions = (const float*)d_in[1];
  const float* rewards = (const float*)d_in[2];
  const float* Ws = (const float*)d_in[3];
  const float* bs = (const float*)d_in[4];
  const float* Wa = (const float*)d_in[5];
  const float* ba = (const float*)d_in[6];
  const float* Wr = (const float*)d_in[7];
  const float* br = (const float*)d_in[8];
  const float* wi = (const float*)d_in[9];
  const float* wh = (const float*)d_in[10];
  const float* bg = (const float*)d_in[11];
  char* wsb = (char*)d_ws;
  // workspace layout (requires ~492.3 MB):
  unsigned short* gx  = (unsigned short*)(wsb);                   // 393,216,000 B
  unsigned short* x   = (unsigned short*)(wsb + 393216000LL);     //  98,304,000 B
  unsigned short* wiT = (unsigned short*)(wsb + 491520000LL);     //     294,912 B
  unsigned short* whF = (unsigned short*)(wsb + 491814912LL);     //     393,216 B
  k_prep <<<1344, 256, 0, stream>>>(wi, wh, wiT, whF);
  k_embed<<<1000, 256, 0, stream>>>(states, actions, rewards, Ws, bs, Wa, ba, Wr, br, x);
  k_gx   <<<4000, 512, 0, stream>>>(x, wiT, bg, gx);
  k_gru  <<<16, 1024, 0, stream>>>(gx, whF, (float*)d_out);
}

// Round 12
// 2185.809 us; speedup vs baseline: 1.2718x; 1.2718x over previous
//
#include <hip/hip_runtime.h>
#include <hip/hip_bf16.h>

#define TT   1000
#define BB   256
#define HID  256
#define GD   768
#define XD   192
#define NROW (TT*BB)

typedef __attribute__((ext_vector_type(8))) _Float16 half8;
typedef __attribute__((ext_vector_type(4))) float    float4_t;
typedef __attribute__((ext_vector_type(2))) unsigned uint2_t;

#define MFMA16(A,B,C) __builtin_amdgcn_mfma_f32_16x16x32_f16((A),(B),(C),0,0,0)

__device__ __forceinline__ void gll16(const void* g, void* l) {
  __builtin_amdgcn_global_load_lds((const __attribute__((address_space(1))) void*)g,
                                   (__attribute__((address_space(3))) void*)l, 16, 0, 0);
}

__device__ __forceinline__ unsigned short f2h(float f) {
  _Float16 h = (_Float16)f;                       // RTN-even
  union { _Float16 h; unsigned short u; } c; c.h = h; return c.u;
}
__device__ __forceinline__ uint2_t pk4h(float4_t v) {
  union { _Float16 h[4]; uint2_t u; } c;
  c.h[0] = (_Float16)v.x; c.h[1] = (_Float16)v.y;
  c.h[2] = (_Float16)v.z; c.h[3] = (_Float16)v.w;
  return c.u;
}
__device__ __forceinline__ float4_t h4_to_f4(uint2_t v) {
  union { uint2_t u; _Float16 h[4]; } c; c.u = v;
  float4_t f;
  f.x = (float)c.h[0]; f.y = (float)c.h[1];
  f.z = (float)c.h[2]; f.w = (float)c.h[3];
  return f;
}
__device__ __forceinline__ float sigx(float x) {
  return __builtin_amdgcn_rcpf(1.0f + __builtin_amdgcn_exp2f(-1.4426950408889634f * x));
}
__device__ __forceinline__ float tanhx(float x) {
  return 1.0f - 2.0f * __builtin_amdgcn_rcpf(1.0f + __builtin_amdgcn_exp2f(2.8853900817779268f * x));
}
__device__ __forceinline__ float4_t sig4(float4_t v){ float4_t o; o.x=sigx(v.x); o.y=sigx(v.y); o.z=sigx(v.z); o.w=sigx(v.w); return o; }
__device__ __forceinline__ float4_t tanh4(float4_t v){ float4_t o; o.x=tanhx(v.x); o.y=tanhx(v.y); o.z=tanhx(v.z); o.w=tanhx(v.w); return o; }
__device__ __forceinline__ float gelu1(float v){
  // jax.nn.gelu default = tanh approximation
  float c = v + 0.044715f * v * v * v;
  float e = __builtin_amdgcn_exp2f((0.7978845608028654f * 2.8853900817779268f) * c);
  float th = 1.0f - 2.0f * __builtin_amdgcn_rcpf(1.0f + e);
  return 0.5f * v * (1.0f + th);
}

// ---------------- prep: wiT[n][k] fp16, whF pre-fragmented fp16 ----------------
__global__ void k_prep(const float* __restrict__ wi, const float* __restrict__ wh,
                       unsigned short* __restrict__ wiT, unsigned short* __restrict__ whF)
{
  int tid = blockIdx.x * 256 + threadIdx.x;
  if (tid < GD*XD) {
    int n = tid / XD, k = tid - n*XD;
    wiT[tid] = f2h(wi[(size_t)k*GD + n]);
  }
  int t2 = tid - GD*XD;
  if (t2 >= 0 && t2 < 48*8*64*8) {
    int j = t2 & 7, l = (t2 >> 3) & 63, f = t2 >> 9;
    int mf = f >> 3, kf = f & 7;
    int k = kf*32 + ((l >> 4) << 3) + j;   // A-frag: lane row=l&15 (=ocol), k=(l>>4)*8+j
    int n = (mf << 4) + (l & 15);
    whF[t2] = f2h(wh[(size_t)k*GD + n]);
  }
}

// ---------------- embeddings -> x fp16 [NROW][192] ----------------
__global__ void k_embed(const float* __restrict__ st, const float* __restrict__ ac,
                        const float* __restrict__ rw,
                        const float* __restrict__ Ws, const float* __restrict__ bs,
                        const float* __restrict__ Wa, const float* __restrict__ ba,
                        const float* __restrict__ Wr, const float* __restrict__ br,
                        unsigned short* __restrict__ x)
{
  int lane = threadIdx.x & 63;
  int wid = blockIdx.x * (blockDim.x >> 6) + (threadIdx.x >> 6);
  int nw  = gridDim.x * (blockDim.x >> 6);
  float wsr[64], war[8];
  #pragma unroll
  for (int k = 0; k < 64; ++k) wsr[k] = Ws[k*64 + lane];   // lane j holds Ws[:,j]
  #pragma unroll
  for (int k = 0; k < 8; ++k) war[k] = Wa[k*64 + lane];
  float wrr = Wr[lane];
  float bsv = bs[lane], bav = ba[lane], brv = br[lane];
  for (int row = wid; row < NROW; row += nw) {
    const float4_t* sp = (const float4_t*)(st + (size_t)row*64);
    float a0 = bsv;
    #pragma unroll
    for (int q = 0; q < 16; ++q) {
      float4_t v = sp[q];
      a0 = fmaf(v.x, wsr[4*q+0], a0);
      a0 = fmaf(v.y, wsr[4*q+1], a0);
      a0 = fmaf(v.z, wsr[4*q+2], a0);
      a0 = fmaf(v.w, wsr[4*q+3], a0);
    }
    const float4_t* ap = (const float4_t*)(ac + (size_t)row*8);
    float a1 = bav;
    #pragma unroll
    for (int q = 0; q < 2; ++q) {
      float4_t v = ap[q];
      a1 = fmaf(v.x, war[4*q+0], a1);
      a1 = fmaf(v.y, war[4*q+1], a1);
      a1 = fmaf(v.z, war[4*q+2], a1);
      a1 = fmaf(v.w, war[4*q+3], a1);
    }
    float a2 = fmaf(rw[row], wrr, brv);
    unsigned short* xr = x + (size_t)row*XD;
    xr[lane]       = f2h(gelu1(a0));
    xr[64 + lane]  = f2h(gelu1(a1));
    xr[128 + lane] = f2h(gelu1(a2));
  }
}

// ---------------- gx = x @ wi + bg (fp16), FRAGMENT-LINEAR output ----------------
// New layout: fragment (block, c, nf) -> contiguous 512 B chunk at
// ((block*48 + c)*4 + nf)*512 + lane*8.  Store = 64 lanes x 8 B contiguous
// (fully coalesced; the old row-major store was 16 scattered 32 B segments at
// stride 1536 -> >=2x write amplification on 393 MB).
__global__ __launch_bounds__(512, 2) void k_gx(const unsigned short* __restrict__ x,
                                               const unsigned short* __restrict__ wiT,
                                               const float* __restrict__ bg,
                                               unsigned short* __restrict__ gx)
{
  __shared__ half8 Xs[24*64];   // 24 B-frags (nf*6+kf), lane-linear
  __shared__ half8 As[16*64];   // 16 A-frags per stage phase
  int lane = threadIdx.x & 63;
  int wv   = threadIdx.x >> 6;
  int b    = lane & 15;
  int g8   = (lane >> 4) << 3;
  int row0 = blockIdx.x * 64;
  #pragma unroll
  for (int i = 0; i < 3; ++i) {
    int c = wv*3 + i, nf = c / 6, kf = c - nf*6;
    gll16(x + (size_t)(row0 + nf*16 + b)*XD + kf*32 + g8, &Xs[c*64]);
  }
  int g4 = g8 >> 1;
  float4_t acc[6][4];
  #pragma unroll
  for (int i = 0; i < 6; ++i) {
    float4_t bgv = *(const float4_t*)(bg + (wv + 8*i)*16 + g4);
    #pragma unroll
    for (int nf = 0; nf < 4; ++nf) acc[i][nf] = bgv;   // bias folded into C-init
  }
  half8 xb[4];
  for (int kf = 0; kf < 6; ++kf) {
    #pragma unroll
    for (int p = 0; p < 3; ++p) {
      __syncthreads();                      // prev phase's reads done
      #pragma unroll
      for (int i2 = 0; i2 < 2; ++i2) {
        int q = wv*2 + i2;
        gll16(wiT + (size_t)((p*16 + q)*16 + b)*XD + kf*32 + g8, &As[q*64]);
      }
      __syncthreads();                      // stage complete (drains vmcnt)
      if (p == 0) {
        #pragma unroll
        for (int nf = 0; nf < 4; ++nf) xb[nf] = Xs[(nf*6 + kf)*64 + lane];
      }
      half8 af0 = As[wv*64 + lane];
      half8 af1 = As[(wv+8)*64 + lane];
      #pragma unroll
      for (int nf = 0; nf < 4; ++nf) {
        acc[2*p  ][nf] = MFMA16(af0, xb[nf], acc[2*p  ][nf]);
        acc[2*p+1][nf] = MFMA16(af1, xb[nf], acc[2*p+1][nf]);
      }
    }
  }
  char* gxc = (char*)gx;
  #pragma unroll
  for (int i = 0; i < 6; ++i) {
    #pragma unroll
    for (int nf = 0; nf < 4; ++nf) {
      size_t idx = (((size_t)blockIdx.x*48 + (wv + 8*i))*4 + nf)*512 + lane*8;
      *(uint2_t*)(gxc + idx) = pk4h(acc[i][nf]);
    }
  }
}

// ---------------- GRU recurrence v6: round-8 structure + frag-linear slab + padded h ----------------
// Reverted to builtin MFMA (rounds 10/11 falsified the AGPR-asm path).
// Changes vs round 8 (1720 us):
//  * slab is fragment-linear: C-init read = slab + c*512 + lane*8 (contiguous,
//    2-way bank = free) and staging soff gathers frags (coalesced 512B runs).
//  * h/rh row stride 528 B (132 dw = 4 mod 32 banks): B-frag ds_read_b128 drops
//    from 8-way conflict (~2.9x) to <=2-way (free). No XOR anywhere.
__global__
__attribute__((amdgpu_flat_work_group_size(512, 512), amdgpu_waves_per_eu(2, 2)))
void k_gru(const unsigned short* __restrict__ gx,
           const unsigned short* __restrict__ whF,
           float* __restrict__ out)
{
  __shared__ char smem[98304];     // STATIC (1 WG/CU): h 8448 + rh 8448 + 2x24576 slabs
  char* h_lds  = smem;             // [16][264] fp16: row stride 528 B
  char* rh_lds = smem + 8448;
  char* gxb    = smem + 16896;     // 2 x 24576 B frag-linear slab
  const int tid  = threadIdx.x;
  const int lane = tid & 63;
  const int wv   = tid >> 6;
  const int wg   = blockIdx.x;
  const int b    = lane & 15;
  const int g    = lane >> 4;
  const int kr4  = g << 2;

  // wave wv owns ocols [wv*32, wv*32+32) of z, r and a. 48 frags = 192 regs.
  half8 wz0[8], wz1[8], wr0[8], wr1[8], wa0[8], wa1[8];
  #pragma unroll
  for (int kf = 0; kf < 8; ++kf) {
    wz0[kf] = *(const half8*)(whF + ((size_t)((( 2*wv    )*8 + kf)*64 + lane) << 3));
    wz1[kf] = *(const half8*)(whF + ((size_t)((( 2*wv + 1)*8 + kf)*64 + lane) << 3));
    wr0[kf] = *(const half8*)(whF + ((size_t)(((16 + 2*wv)*8 + kf)*64 + lane) << 3));
    wr1[kf] = *(const half8*)(whF + ((size_t)(((17 + 2*wv)*8 + kf)*64 + lane) << 3));
    wa0[kf] = *(const half8*)(whF + ((size_t)(((32 + 2*wv)*8 + kf)*64 + lane) << 3));
    wa1[kf] = *(const half8*)(whF + ((size_t)(((33 + 2*wv)*8 + kf)*64 + lane) << 3));
  }
  #pragma unroll
  for (int kf = 0; kf < 8; ++kf) {
    asm volatile("" : "+v"(wz0[kf]));
    asm volatile("" : "+v"(wz1[kf]));
    asm volatile("" : "+v"(wr0[kf]));
    asm volatile("" : "+v"(wr1[kf]));
    asm volatile("" : "+v"(wa0[kf]));
    asm volatile("" : "+v"(wa1[kf]));
  }
  for (int i = tid; i < 2112; i += 512) ((unsigned*)h_lds)[i] = 0u;   // h0 = 0 (8448 B)

  // slab staging: frag-linear. Dest byte D = i*8192 + tid*16 (wave-uniform base
  // + lane*16). Source within the (bt,nf) block: c = D/512, r = D%512 ->
  // soff = nf*512 + c*2048 + r.
  const int nf   = wg & 3;
  const int bsel = wg >> 2;
  int soff[3], dch[3];
  #pragma unroll
  for (int i = 0; i < 3; ++i) {
    int c = i*16 + (tid >> 5);
    int r = (tid & 31) << 4;
    soff[i] = nf*512 + c*2048 + r;
    dch[i]  = i*8192 + tid*16;
  }
  const char* gxc = (const char*)gx;
  #pragma unroll
  for (int i = 0; i < 3; ++i)
    gll16(gxc + (size_t)bsel*98304 + soff[i], gxb + dch[i]);
  __syncthreads();   // full drain: t=0 slab ready, h zeroed

  float4_t hf0 = {0.f, 0.f, 0.f, 0.f}, hf1 = hf0;   // fp32 h for owned cols
  const char* hb_base = h_lds + b*528;
  const char* rb_base = rh_lds + b*528;
  const int off_h0 = (wv*32 + kr4) << 1;        // h/rh row-internal byte offset
  const int off_h1 = off_h0 + 32;
  const int lz0 = ( 2*wv    )*512 + lane*8;     // slab frag offsets (C-init)
  const int lz1 = ( 2*wv + 1)*512 + lane*8;
  const int lr0 = (16 + 2*wv)*512 + lane*8;
  const int lr1 = (17 + 2*wv)*512 + lane*8;
  const int la0 = (32 + 2*wv)*512 + lane*8;
  const int la1 = (33 + 2*wv)*512 + lane*8;

  for (int t = 0; t < TT; ++t) {
    // TOP barrier: counted vmcnt(2) -> 3 glls done, 2 hs-stores may stay in flight
    asm volatile("s_waitcnt vmcnt(2) lgkmcnt(0)" ::: "memory");
    __builtin_amdgcn_s_barrier();
    asm volatile("" ::: "memory");   // no memory op hoists above the barrier
    if (t + 1 < TT) {   // prefetch next slab; stays in flight across mid barrier
      const char* slab = gxc + ((size_t)(t+1)*4 + bsel)*98304;
      char* dstb = gxb + 24576*((t+1) & 1);
      #pragma unroll
      for (int i = 0; i < 3; ++i) gll16(slab + soff[i], dstb + dch[i]);
    }
    const char* cur = gxb + 24576*(t & 1);
    // ---- phase 1: zr^T = sigmoid(gx_zr + wh_zr^T @ h^T) ----
    float4_t az0 = h4_to_f4(*(const uint2_t*)(cur + lz0));
    float4_t az1 = h4_to_f4(*(const uint2_t*)(cur + lz1));
    float4_t ar0 = h4_to_f4(*(const uint2_t*)(cur + lr0));
    float4_t ar1 = h4_to_f4(*(const uint2_t*)(cur + lr1));
    #pragma unroll
    for (int kf = 0; kf < 8; ++kf) {
      half8 hb = *(const half8*)(hb_base + kf*64 + (g << 4));
      az0 = MFMA16(wz0[kf], hb, az0);
      az1 = MFMA16(wz1[kf], hb, az1);
      ar0 = MFMA16(wr0[kf], hb, ar0);
      ar1 = MFMA16(wr1[kf], hb, ar1);
    }
    float4_t z0 = sig4(az0), z1 = sig4(az1);
    float4_t rh0 = sig4(ar0) * hf0, rh1 = sig4(ar1) * hf1;   // r*h, all in-lane
    *(uint2_t*)(rh_lds + b*528 + off_h0) = pk4h(rh0);
    *(uint2_t*)(rh_lds + b*528 + off_h1) = pk4h(rh1);
    // MID barrier: LDS-only wait, prefetch glls stay outstanding
    asm volatile("s_waitcnt lgkmcnt(0)" ::: "memory");
    __builtin_amdgcn_s_barrier();
    asm volatile("" ::: "memory");
    // ---- phase 2: a^T = tanh(gx_a + wh_a^T @ (r*h)^T) ----
    float4_t aa0 = h4_to_f4(*(const uint2_t*)(cur + la0));
    float4_t aa1 = h4_to_f4(*(const uint2_t*)(cur + la1));
    #pragma unroll
    for (int kf = 0; kf < 8; ++kf) {
      half8 rb = *(const half8*)(rb_base + kf*64 + (g << 4));
      aa0 = MFMA16(wa0[kf], rb, aa0);
      aa1 = MFMA16(wa1[kf], rb, aa1);
    }
    float4_t a0 = tanh4(aa0), a1 = tanh4(aa1);
    float4_t hn0 = hf0 + z0 * (a0 - hf0);   // (1-z)h + z*a
    float4_t hn1 = hf1 + z1 * (a1 - hf1);
    hf0 = hn0; hf1 = hn1;
    *(uint2_t*)(h_lds + b*528 + off_h0) = pk4h(hn0);
    *(uint2_t*)(h_lds + b*528 + off_h1) = pk4h(hn1);
    float* op = out + (((size_t)t*BB + wg*16 + b) << 8) + wv*32 + kr4;
    *(float4_t*)op = hn0;
    *(float4_t*)(op + 16) = hn1;
  }
}

extern "C" void kernel_launch(void* const* d_in, const int* in_sizes, int n_in,
                              void* d_out, int out_size, void* d_ws, size_t ws_size,
                              hipStream_t stream) {
  (void)in_sizes; (void)n_in; (void)out_size; (void)ws_size;
  const float* states  = (const float*)d_in[0];
  const float* actions = (const float*)d_in[1];
  const float* rewards = (const float*)d_in[2];
  const float* Ws = (const float*)d_in[3];
  const float* bs = (const float*)d_in[4];
  const float* Wa = (const float*)d_in[5];
  const float* ba = (const float*)d_in[6];
  const float* Wr = (const float*)d_in[7];
  const float* br = (const float*)d_in[8];
  const float* wi = (const float*)d_in[9];
  const float* wh = (const float*)d_in[10];
  const float* bg = (const float*)d_in[11];
  char* wsb = (char*)d_ws;
  // workspace layout (requires ~492.3 MB):
  unsigned short* gx  = (unsigned short*)(wsb);                   // 393,216,000 B
  unsigned short* x   = (unsigned short*)(wsb + 393216000LL);     //  98,304,000 B
  unsigned short* wiT = (unsigned short*)(wsb + 491520000LL);     //     294,912 B
  unsigned short* whF = (unsigned short*)(wsb + 491814912LL);     //     393,216 B
  k_prep <<<1344, 256, 0, stream>>>(wi, wh, wiT, whF);
  k_embed<<<1000, 256, 0, stream>>>(states, actions, rewards, Ws, bs, Wa, ba, Wr, br, x);
  k_gx   <<<4000, 512, 0, stream>>>(x, wiT, bg, gx);
  k_gru  <<<16, 512, 0, stream>>>(gx, whF, (float*)d_out);
}